// Round 6
// baseline (247.754 us; speedup 1.0000x reference)
//
#include <hip/hip_runtime.h>
#include <hip/hip_bf16.h>

// Problem constants
constexpr int Bb = 8, Nn = 4096, Ss = 1024;
constexpr int D1 = 128, D2 = 256, KIN = 384, OC = 256;
constexpr int L = Bb * Nn;             // 32768 rows
constexpr float BN_EPS = 1e-5f;

typedef __attribute__((ext_vector_type(4))) float floatx4;
typedef __attribute__((ext_vector_type(8))) __bf16 bf16x8;

#define DEV __device__ __forceinline__

DEV float bf2f(unsigned short u) {
    union { unsigned int i; float f; } v; v.i = ((unsigned int)u) << 16; return v.f;
}
DEV unsigned short f2bf(float f) {
    union { float f; unsigned int i; } v; v.f = f;
    unsigned int x = v.i;
    return (unsigned short)((x + 0x7FFFu + ((x >> 16) & 1u)) >> 16);  // RNE
}
// Fast tanh-form gelu: x*sigmoid(2u), u = sqrt(2/pi)*(x+0.044715x^3).
DEV float gelu_f(float x) {
    float u = x * (0.7978845608f + 0.0356774081f * x * x);
    float t = __expf(-2.0f * u);
    return x * __builtin_amdgcn_rcpf(1.0f + t);
}

// ---------------- init: zero stats (blocks 0-5) + dtype probe (block 6) ----------------
__global__ void k_init(float* stats, const unsigned int* __restrict__ w, int* __restrict__ flag) {
    if (blockIdx.x < 6) {
        stats[blockIdx.x * 256 + threadIdx.x] = 0.0f;
    } else if (threadIdx.x == 0) {
        int sane = 0;
        for (int i = 0; i < 64; ++i) {
            unsigned int lo = w[i] & 0xFFFFu;
            int e = (int)((lo >> 7) & 0xFF);
            if (e >= 100 && e <= 144) ++sane;
        }
        *flag = (sane >= 48) ? 0 : 1;   // 0 = bf16 inputs, 1 = f32 inputs
    }
}

// ---------------- all three weight matrices -> bf16, one launch ----------------
// dsts are contiguous in ws: [Wf (98304) | W1 (65536) | W2 (65536)]
__global__ void k_prep_w(const void* __restrict__ s0, const void* __restrict__ s1,
                         const void* __restrict__ s2, unsigned short* __restrict__ dst,
                         const int* __restrict__ dflag) {
    int i = blockIdx.x * 256 + threadIdx.x;
    const void* src; int off;
    if (i < 98304)      { src = s0; off = i; }
    else if (i < 163840){ src = s1; off = i - 98304; }
    else                { src = s2; off = i - 163840; }
    if (*dflag) dst[i] = f2bf(((const float*)src)[off]);
    else        dst[i] = ((const unsigned short*)src)[off];
}

// Branchless merge of two sorted (asc) top-3 lists; pref=true -> ties keep "a" side.
DEV void merge3(float& d0, float& d1, float& d2, int& i0, int& i1, int& i2,
                float e0, float e1, float e2, int j0, int j1, int j2, bool pref) {
    float a0 = d0, a1 = d1, a2 = d2; int x0 = i0, x1 = i1, x2 = i2;
    float b0 = e0, b1 = e1;          int y0 = j0, y1 = j1;
    bool t = pref ? (a0 <= b0) : (a0 < b0);
    d0 = t ? a0 : b0; i0 = t ? x0 : y0;
    a0 = t ? a1 : a0; x0 = t ? x1 : x0;
    a1 = t ? a2 : a1; x1 = t ? x2 : x1;
    b0 = t ? b0 : b1; y0 = t ? y0 : y1;
    b1 = t ? b1 : e2; y1 = t ? y1 : j2;
    t = pref ? (a0 <= b0) : (a0 < b0);
    d1 = t ? a0 : b0; i1 = t ? x0 : y0;
    a0 = t ? a1 : a0; x0 = t ? x1 : x0;
    b0 = t ? b0 : b1; y0 = t ? y0 : y1;
    t = pref ? (a0 <= b0) : (a0 < b0);
    d2 = t ? a0 : b0; i2 = t ? x0 : y0;
}

// ---------------- 3-NN search + weights ----------------
// 8 lanes cooperate per query (part = tid&7 scans 128 of 1024 sources), then a
// 3-stage shfl_xor merge. Grid: 1024 blocks x 256 threads = 32 queries/block.
__global__ __launch_bounds__(256) void k_nn(const void* __restrict__ xyz1_,
                                            const void* __restrict__ xyz2_,
                                            const int* __restrict__ dflag,
                                            int* __restrict__ nn_idx, float* __restrict__ nn_w) {
    __shared__ alignas(16) float s4[Ss * 4 + 32];
    int tid = threadIdx.x;
    int b = (blockIdx.x * 32) >> 12;
    bool isf = (*dflag != 0);

    if (isf) {
        const float* p2 = (const float*)xyz2_ + (size_t)b * Ss * 3;
        for (int i = tid; i < Ss * 3; i += 256) {
            int s = i / 3, k = i - s * 3;
            s4[s * 4 + k + ((s >> 7) << 2)] = p2[i];
        }
    } else {
        const unsigned short* p2 = (const unsigned short*)xyz2_ + (size_t)b * Ss * 3;
        for (int i = tid; i < Ss * 3; i += 256) {
            int s = i / 3, k = i - s * 3;
            s4[s * 4 + k + ((s >> 7) << 2)] = bf2f(p2[i]);
        }
    }
    __syncthreads();
    for (int s = tid; s < Ss; s += 256) {
        int a = s * 4 + ((s >> 7) << 2);
        float x = s4[a], y = s4[a + 1], z = s4[a + 2];
        s4[a + 3] = x * x + y * y + z * z;
    }
    __syncthreads();

    int part = tid & 7;
    int bn = blockIdx.x * 32 + (tid >> 3);
    float x1, y1, z1;
    if (isf) {
        const float* p1 = (const float*)xyz1_ + (size_t)bn * 3;
        x1 = p1[0]; y1 = p1[1]; z1 = p1[2];
    } else {
        const unsigned short* p1 = (const unsigned short*)xyz1_ + (size_t)bn * 3;
        x1 = bf2f(p1[0]); y1 = bf2f(p1[1]); z1 = bf2f(p1[2]);
    }
    float n1 = x1 * x1 + y1 * y1 + z1 * z1;

    float d0 = 3.4e38f, d1 = 3.4e38f, d2 = 3.4e38f;
    int i0 = 0, i1 = 0, i2 = 0;
    const float* sp = &s4[part * 516];
#pragma unroll 4
    for (int j = 0; j < 128; ++j) {
        float4 q = *(const float4*)(sp + j * 4);
        float d = n1 + q.w - 2.0f * (x1 * q.x + y1 * q.y + z1 * q.z);
        int s = part * 128 + j;
        bool c2 = d < d2, c1 = d < d1, c0 = d < d0;
        d2 = c1 ? d1 : (c2 ? d : d2); i2 = c1 ? i1 : (c2 ? s : i2);
        d1 = c0 ? d0 : (c1 ? d : d1); i1 = c0 ? i0 : (c1 ? s : i1);
        d0 = c0 ? d  : d0;            i0 = c0 ? s  : i0;
    }
#pragma unroll
    for (int m = 1; m <= 4; m <<= 1) {
        float e0 = __shfl_xor(d0, m, 64), e1 = __shfl_xor(d1, m, 64), e2 = __shfl_xor(d2, m, 64);
        int   j0 = __shfl_xor(i0, m, 64), j1 = __shfl_xor(i1, m, 64), j2 = __shfl_xor(i2, m, 64);
        bool pref = (part < (part ^ m));
        merge3(d0, d1, d2, i0, i1, i2, e0, e1, e2, j0, j1, j2, pref);
    }
    if (part == 0) {
        float r0 = 1.0f / (d0 + 1e-8f), r1 = 1.0f / (d1 + 1e-8f), r2 = 1.0f / (d2 + 1e-8f);
        float rs = 1.0f / (r0 + r1 + r2);
        nn_idx[bn * 3 + 0] = i0; nn_idx[bn * 3 + 1] = i1; nn_idx[bn * 3 + 2] = i2;
        nn_w[bn * 3 + 0] = r0 * rs; nn_w[bn * 3 + 1] = r1 * rs; nn_w[bn * 3 + 2] = r2 * rs;
    }
}

// ---------------- build X = concat(points1, interp) as (L, 384) bf16 ----------------
__global__ __launch_bounds__(256) void k_build_x(const void* __restrict__ points1_,
                                                 const void* __restrict__ points2_,
                                                 const int* __restrict__ dflag,
                                                 const int* __restrict__ nn_idx,
                                                 const float* __restrict__ nn_w,
                                                 unsigned short* __restrict__ X) {
    int tid = threadIdx.x;
    int pt = blockIdx.x * 4 + (tid >> 6);
    int lane = tid & 63;
    int b = pt >> 12;
    bool isf = (*dflag != 0);

    int i0 = nn_idx[pt * 3], i1 = nn_idx[pt * 3 + 1], i2 = nn_idx[pt * 3 + 2];
    float w0 = nn_w[pt * 3], w1 = nn_w[pt * 3 + 1], w2 = nn_w[pt * 3 + 2];
    int c = lane * 4;

    if (isf) {
        const float* p1 = (const float*)points1_ + (size_t)pt * D1;
        float2 v = *(const float2*)(p1 + lane * 2);
        unsigned int packed = (unsigned int)f2bf(v.x) | ((unsigned int)f2bf(v.y) << 16);
        ((unsigned int*)(X + (size_t)pt * KIN))[lane] = packed;

        const float* base = (const float*)points2_;
        const float* r0 = base + ((size_t)(b * Ss + i0)) * D2 + c;
        const float* r1 = base + ((size_t)(b * Ss + i1)) * D2 + c;
        const float* r2 = base + ((size_t)(b * Ss + i2)) * D2 + c;
        float4 a0 = *(const float4*)r0;
        float4 a1 = *(const float4*)r1;
        float4 a2 = *(const float4*)r2;
        uint2 out;
        unsigned short* uo = (unsigned short*)&out;
        uo[0] = f2bf(w0 * a0.x + w1 * a1.x + w2 * a2.x);
        uo[1] = f2bf(w0 * a0.y + w1 * a1.y + w2 * a2.y);
        uo[2] = f2bf(w0 * a0.z + w1 * a1.z + w2 * a2.z);
        uo[3] = f2bf(w0 * a0.w + w1 * a1.w + w2 * a2.w);
        *(uint2*)(X + (size_t)pt * KIN + D1 + c) = out;
    } else {
        const unsigned short* p1 = (const unsigned short*)points1_;
        ((unsigned int*)(X + (size_t)pt * KIN))[lane] =
            ((const unsigned int*)(p1 + (size_t)pt * D1))[lane];

        const unsigned short* base = (const unsigned short*)points2_;
        const unsigned short* r0 = base + ((size_t)(b * Ss + i0)) * D2 + c;
        const unsigned short* r1 = base + ((size_t)(b * Ss + i1)) * D2 + c;
        const unsigned short* r2 = base + ((size_t)(b * Ss + i2)) * D2 + c;
        uint2 v0 = *(const uint2*)r0;
        uint2 v1 = *(const uint2*)r1;
        uint2 v2 = *(const uint2*)r2;
        const unsigned short* u0 = (const unsigned short*)&v0;
        const unsigned short* u1 = (const unsigned short*)&v1;
        const unsigned short* u2 = (const unsigned short*)&v2;
        uint2 out;
        unsigned short* uo = (unsigned short*)&out;
#pragma unroll
        for (int j = 0; j < 4; ++j)
            uo[j] = f2bf(w0 * bf2f(u0[j]) + w1 * bf2f(u1[j]) + w2 * bf2f(u2[j]));
        *(uint2*)(X + (size_t)pt * KIN + D1 + c) = out;
    }
}

// ---------------- GEMM: C[l][o] = sum_c act(A[l][c]) * W[o][c], + channel stats ----------------
// 64-row x 256-col tile per block (full output width: A read ONCE, gelu ONCE —
// the old grid.y=2 split fetched A twice and ran the staging gelu twice).
// grid: L/64 = 512 blocks; 4 waves, wave wn owns 64 rows x cols [wn*64, wn*64+64).
template <int K, int ACT>
__global__ __launch_bounds__(256) void k_gemm(const unsigned short* __restrict__ A,
                                              const unsigned short* __restrict__ W,
                                              unsigned short* __restrict__ Out,
                                              float* __restrict__ S1, float* __restrict__ S2,
                                              const float* __restrict__ cA,
                                              const float* __restrict__ cC) {
    __shared__ alignas(16) unsigned short As[64 * 64];    // 8 KB
    __shared__ alignas(16) unsigned short Bs[256 * 64];   // 32 KB
    __shared__ float sS1[256], sS2[256];

    int tid = threadIdx.x;
    int l0 = blockIdx.x * 64;
    int wn = tid >> 6, lane = tid & 63, quad = lane >> 4, lr = lane & 15;

    floatx4 zero4 = {0.f, 0.f, 0.f, 0.f};
    floatx4 acc[4][4];
#pragma unroll
    for (int mi = 0; mi < 4; ++mi)
#pragma unroll
        for (int ni = 0; ni < 4; ++ni) acc[mi][ni] = zero4;

    constexpr int KC = K / 64;
    for (int kc = 0; kc < KC; ++kc) {
        __syncthreads();
        // stage A tile (64 x 64): 512 chunks of 8 -> 2 iters
#pragma unroll
        for (int it = 0; it < 2; ++it) {
            int idx = it * 256 + tid;
            int row = idx >> 3, c8 = idx & 7;
            union { uint4 v; unsigned short u[8]; } va;
            va.v = *(const uint4*)(A + (size_t)(l0 + row) * K + kc * 64 + c8 * 8);
            if (ACT) {
                int kbase = kc * 64 + c8 * 8;
#pragma unroll
                for (int j = 0; j < 8; ++j) {
                    float f = bf2f(va.u[j]);
                    va.u[j] = f2bf(gelu_f(cA[kbase + j] * f + cC[kbase + j]));
                }
            }
            *(uint4*)&As[row * 64 + ((c8 ^ (row & 7)) << 3)] = va.v;
        }
        // stage B tile (256 x 64): 2048 chunks of 8 -> 8 iters
#pragma unroll
        for (int it = 0; it < 8; ++it) {
            int idx = it * 256 + tid;
            int row = idx >> 3, c8 = idx & 7;
            uint4 vb = *(const uint4*)(W + (size_t)row * K + kc * 64 + c8 * 8);
            *(uint4*)&Bs[row * 64 + ((c8 ^ (row & 7)) << 3)] = vb;
        }
        __syncthreads();
#pragma unroll
        for (int ks8 = 0; ks8 < 2; ++ks8) {
            bf16x8 af[4], bfr[4];
#pragma unroll
            for (int mi = 0; mi < 4; ++mi) {
                int ra = mi * 16 + lr;
                af[mi] = *(const bf16x8*)&As[ra * 64 + ((((ks8 << 2) + quad) ^ (ra & 7)) << 3)];
            }
#pragma unroll
            for (int ni = 0; ni < 4; ++ni) {
                int rb = wn * 64 + ni * 16 + lr;
                bfr[ni] = *(const bf16x8*)&Bs[rb * 64 + ((((ks8 << 2) + quad) ^ (rb & 7)) << 3)];
            }
#pragma unroll
            for (int mi = 0; mi < 4; ++mi)
#pragma unroll
                for (int ni = 0; ni < 4; ++ni)
                    acc[mi][ni] = __builtin_amdgcn_mfma_f32_16x16x32_bf16(af[mi], bfr[ni], acc[mi][ni], 0, 0, 0);
        }
    }

    // epilogue: write bf16 + per-channel partial sums (for BN stats)
    float p1[4] = {0, 0, 0, 0}, p2[4] = {0, 0, 0, 0};
#pragma unroll
    for (int mi = 0; mi < 4; ++mi) {
#pragma unroll
        for (int ni = 0; ni < 4; ++ni) {
#pragma unroll
            for (int r = 0; r < 4; ++r) {
                float v = acc[mi][ni][r];
                int row = l0 + mi * 16 + quad * 4 + r;
                int col = wn * 64 + ni * 16 + lr;
                Out[(size_t)row * OC + col] = f2bf(v);
                p1[ni] += v;
                p2[ni] += v * v;
            }
        }
    }
    sS1[tid] = 0.f; sS2[tid] = 0.f;
    __syncthreads();
#pragma unroll
    for (int ni = 0; ni < 4; ++ni) {
        atomicAdd(&sS1[wn * 64 + ni * 16 + lr], p1[ni]);
        atomicAdd(&sS2[wn * 64 + ni * 16 + lr], p2[ni]);
    }
    __syncthreads();
    atomicAdd(&S1[tid], sS1[tid]);
    atomicAdd(&S2[tid], sS2[tid]);
}

// ---------------- BN coefficient finalize: a = g*rsqrt(var+eps), c = bt - mean*a ----------------
__global__ void k_finalize(const float* __restrict__ S1, const float* __restrict__ S2,
                           const void* __restrict__ g_, const void* __restrict__ bt_,
                           const int* __restrict__ dflag,
                           float* __restrict__ cA, float* __restrict__ cC) {
    int o = threadIdx.x;
    float m = S1[o] * (1.0f / (float)L);
    float var = S2[o] * (1.0f / (float)L) - m * m;
    float g, bt;
    if (*dflag) { g = ((const float*)g_)[o]; bt = ((const float*)bt_)[o]; }
    else { g = bf2f(((const unsigned short*)g_)[o]); bt = bf2f(((const unsigned short*)bt_)[o]); }
    float a = g * rsqrtf(var + BN_EPS);
    cA[o] = a;
    cC[o] = bt - m * a;
}

// ---------------- final: out = gelu( bn2(t2) + gelu(bn0(t0)) ); out dtype per dflag ----------------
__global__ __launch_bounds__(256) void k_final(const unsigned short* __restrict__ t0,
                                               const unsigned short* __restrict__ t2,
                                               const float* __restrict__ cA0, const float* __restrict__ cC0,
                                               const float* __restrict__ cA2, const float* __restrict__ cC2,
                                               const int* __restrict__ dflag,
                                               void* __restrict__ out_) {
    int idx = (blockIdx.x * 256 + threadIdx.x) * 8;
    int col = idx & (OC - 1);
    union { uint4 v; unsigned short u[8]; } v0, v2;
    v0.v = *(const uint4*)(t0 + idx);
    v2.v = *(const uint4*)(t2 + idx);
    float r[8];
#pragma unroll
    for (int j = 0; j < 8; ++j) {
        float x = gelu_f(cA0[col + j] * bf2f(v0.u[j]) + cC0[col + j]);
        float y = cA2[col + j] * bf2f(v2.u[j]) + cC2[col + j];
        r[j] = gelu_f(x + y);
    }
    if (*dflag) {
        float* o = (float*)out_ + idx;
        float4 lo = {r[0], r[1], r[2], r[3]};
        float4 hi = {r[4], r[5], r[6], r[7]};
        *(float4*)o = lo;
        *(float4*)(o + 4) = hi;
    } else {
        union { uint4 v; unsigned short u[8]; } vo;
#pragma unroll
        for (int j = 0; j < 8; ++j) vo.u[j] = f2bf(r[j]);
        *(uint4*)((unsigned short*)out_ + idx) = vo.v;
    }
}

extern "C" void kernel_launch(void* const* d_in, const int* in_sizes, int n_in,
                              void* d_out, int out_size, void* d_ws, size_t ws_size,
                              hipStream_t stream) {
    const void* xyz1    = d_in[0];
    const void* xyz2    = d_in[1];
    const void* points1 = d_in[2];
    const void* points2 = d_in[3];
    const void* W_fuse  = d_in[4];
    const void* g_fuse  = d_in[6];
    const void* bt_fuse = d_in[7];
    const void* W1      = d_in[8];
    const void* g1      = d_in[10];
    const void* bt1     = d_in[11];
    const void* W2      = d_in[12];
    const void* g2      = d_in[14];
    const void* bt2     = d_in[15];

    char* ws = (char*)d_ws;
    unsigned short* X  = (unsigned short*)ws;
    unsigned short* t0 = (unsigned short*)(ws + 25165824);
    unsigned short* t1 = (unsigned short*)d_out;   // d_out as bf16 scratch until k_final
    unsigned short* t2 = X;                        // X dead after GEMM1
    int*   nn_idx = (int*)(ws + 41943040);
    float* nn_w   = (float*)(ws + 42336256);
    float* stats  = (float*)(ws + 42729472);
    int*   dflag  = (int*)(ws + 42729472 + 3072 * 4);
    unsigned short* Wf_bf = (unsigned short*)(ws + 42745856);  // contiguous: Wf | W1 | W2

    float *S1_0 = stats,        *S2_0 = stats + 256;
    float *S1_1 = stats + 512,  *S2_1 = stats + 768;
    float *S1_2 = stats + 1024, *S2_2 = stats + 1280;
    float *cA0 = stats + 1536, *cC0 = stats + 1792;
    float *cA1 = stats + 2048, *cC1 = stats + 2304;
    float *cA2 = stats + 2560, *cC2 = stats + 2816;

    k_init<<<7, 256, 0, stream>>>(stats, (const unsigned int*)xyz1, dflag);
    k_prep_w<<<(98304 + 2 * 65536) / 256, 256, 0, stream>>>(W_fuse, W1, W2, Wf_bf, dflag);
    k_nn<<<L / 32, 256, 0, stream>>>(xyz1, xyz2, dflag, nn_idx, nn_w);
    k_build_x<<<L / 4, 256, 0, stream>>>(points1, points2, dflag, nn_idx, nn_w, X);

    k_gemm<KIN, 0><<<L / 64, 256, 0, stream>>>(X, Wf_bf, t0, S1_0, S2_0, nullptr, nullptr);
    k_finalize<<<1, 256, 0, stream>>>(S1_0, S2_0, g_fuse, bt_fuse, dflag, cA0, cC0);
    k_gemm<OC, 1><<<L / 64, 256, 0, stream>>>(t0, Wf_bf + 98304, t1, S1_1, S2_1, cA0, cC0);
    k_finalize<<<1, 256, 0, stream>>>(S1_1, S2_1, g1, bt1, dflag, cA1, cC1);
    k_gemm<OC, 1><<<L / 64, 256, 0, stream>>>(t1, Wf_bf + 163840, t2, S1_2, S2_2, cA1, cC1);
    k_finalize<<<1, 256, 0, stream>>>(S1_2, S2_2, g2, bt2, dflag, cA2, cC2);
    k_final<<<L * OC / (256 * 8), 256, 0, stream>>>(t0, t2, cA0, cC0, cA2, cC2, dflag, d_out);
}

// Round 7
// 233.347 us; speedup vs baseline: 1.0617x; 1.0617x over previous
//
#include <hip/hip_runtime.h>
#include <hip/hip_bf16.h>

// Problem constants
constexpr int Bb = 8, Nn = 4096, Ss = 1024;
constexpr int D1 = 128, D2 = 256, KIN = 384, OC = 256;
constexpr int L = Bb * Nn;             // 32768 rows
constexpr float BN_EPS = 1e-5f;
constexpr int NW = 98304 + 65536 + 65536;  // total weight elements (Wf|W1|W2)

typedef __attribute__((ext_vector_type(4))) float floatx4;
typedef __attribute__((ext_vector_type(8))) __bf16 bf16x8;

#define DEV __device__ __forceinline__

DEV float bf2f(unsigned short u) {
    union { unsigned int i; float f; } v; v.i = ((unsigned int)u) << 16; return v.f;
}
DEV unsigned short f2bf(float f) {
    union { float f; unsigned int i; } v; v.f = f;
    unsigned int x = v.i;
    return (unsigned short)((x + 0x7FFFu + ((x >> 16) & 1u)) >> 16);  // RNE
}
// Fast tanh-form gelu: x*sigmoid(2u), u = sqrt(2/pi)*(x+0.044715x^3).
DEV float gelu_f(float x) {
    float u = x * (0.7978845608f + 0.0356774081f * x * x);
    float t = __expf(-2.0f * u);
    return x * __builtin_amdgcn_rcpf(1.0f + t);
}

// Per-block dtype probe: 64 lanes each test one word of xyz1; f32 low-halves are
// mantissa junk (rarely decode as sane bf16 exponents). No launch, no global dep.
DEV bool probe_isf(const unsigned int* __restrict__ w, int tid) {
    unsigned int lo = w[tid & 63] & 0xFFFFu;
    int e = (int)((lo >> 7) & 0xFF);
    unsigned long long m = __ballot(e >= 100 && e <= 144);
    return __popcll(m) < 48;   // <48 sane -> f32 inputs
}

// Branchless merge of two sorted (asc) top-3 lists; pref=true -> ties keep "a" side.
DEV void merge3(float& d0, float& d1, float& d2, int& i0, int& i1, int& i2,
                float e0, float e1, float e2, int j0, int j1, int j2, bool pref) {
    float a0 = d0, a1 = d1, a2 = d2; int x0 = i0, x1 = i1, x2 = i2;
    float b0 = e0, b1 = e1;          int y0 = j0, y1 = j1;
    bool t = pref ? (a0 <= b0) : (a0 < b0);
    d0 = t ? a0 : b0; i0 = t ? x0 : y0;
    a0 = t ? a1 : a0; x0 = t ? x1 : x0;
    a1 = t ? a2 : a1; x1 = t ? x2 : x1;
    b0 = t ? b0 : b1; y0 = t ? y0 : y1;
    b1 = t ? b1 : e2; y1 = t ? y1 : j2;
    t = pref ? (a0 <= b0) : (a0 < b0);
    d1 = t ? a0 : b0; i1 = t ? x0 : y0;
    a0 = t ? a1 : a0; x0 = t ? x1 : x0;
    b0 = t ? b0 : b1; y0 = t ? y0 : y1;
    t = pref ? (a0 <= b0) : (a0 < b0);
    d2 = t ? a0 : b0; i2 = t ? x0 : y0;
}

// ---------------- launch 1: zero-stats | prep-weights | nn+build fused ----------------
// blocks [0,6): zero the 1536 stat floats. blocks [6,902): weight->bf16.
// blocks [902,1926): 32 queries each — 3-NN (8 lanes/query) then interp+concat
// into X, idx/w handed over in LDS (no nn_idx/nn_w globals, no extra launch).
__global__ __launch_bounds__(256) void k_front(const void* __restrict__ xyz1_,
                                               const void* __restrict__ xyz2_,
                                               const void* __restrict__ points1_,
                                               const void* __restrict__ points2_,
                                               const void* __restrict__ w0_,
                                               const void* __restrict__ w1_,
                                               const void* __restrict__ w2_,
                                               unsigned short* __restrict__ Wdst,
                                               unsigned short* __restrict__ X,
                                               float* __restrict__ stats,
                                               int* __restrict__ dflag) {
    int tid = threadIdx.x;
    int bid = blockIdx.x;
    bool isf = probe_isf((const unsigned int*)xyz1_, tid);

    if (bid < 6) {
        stats[bid * 256 + tid] = 0.0f;
        if (bid == 0 && tid == 0) *dflag = isf ? 1 : 0;  // for later launches
        return;
    }
    if (bid < 902) {
        int i = (bid - 6) * 256 + tid;
        const void* src; int off;
        if (i < 98304)       { src = w0_; off = i; }
        else if (i < 163840) { src = w1_; off = i - 98304; }
        else                 { src = w2_; off = i - 163840; }
        Wdst[i] = isf ? f2bf(((const float*)src)[off]) : ((const unsigned short*)src)[off];
        return;
    }

    // ---- nn + build for 32 consecutive query points ----
    __shared__ alignas(16) float s4[Ss * 4 + 32];
    __shared__ int   sIdx[32 * 3];
    __shared__ float sW[32 * 3];
    int bn0 = (bid - 902) * 32;
    int b = bn0 >> 12;

    if (isf) {
        const float* p2 = (const float*)xyz2_ + (size_t)b * Ss * 3;
        for (int i = tid; i < Ss * 3; i += 256) {
            int s = i / 3, k = i - s * 3;
            s4[s * 4 + k + ((s >> 7) << 2)] = p2[i];
        }
    } else {
        const unsigned short* p2 = (const unsigned short*)xyz2_ + (size_t)b * Ss * 3;
        for (int i = tid; i < Ss * 3; i += 256) {
            int s = i / 3, k = i - s * 3;
            s4[s * 4 + k + ((s >> 7) << 2)] = bf2f(p2[i]);
        }
    }
    __syncthreads();
    for (int s = tid; s < Ss; s += 256) {
        int a = s * 4 + ((s >> 7) << 2);
        float x = s4[a], y = s4[a + 1], z = s4[a + 2];
        s4[a + 3] = x * x + y * y + z * z;
    }
    __syncthreads();

    int part = tid & 7;
    int q = tid >> 3;               // local query 0..31
    int bn = bn0 + q;
    float x1, y1, z1;
    if (isf) {
        const float* p1 = (const float*)xyz1_ + (size_t)bn * 3;
        x1 = p1[0]; y1 = p1[1]; z1 = p1[2];
    } else {
        const unsigned short* p1 = (const unsigned short*)xyz1_ + (size_t)bn * 3;
        x1 = bf2f(p1[0]); y1 = bf2f(p1[1]); z1 = bf2f(p1[2]);
    }
    float n1 = x1 * x1 + y1 * y1 + z1 * z1;

    float d0 = 3.4e38f, d1 = 3.4e38f, d2 = 3.4e38f;
    int i0 = 0, i1 = 0, i2 = 0;
    const float* sp = &s4[part * 516];
#pragma unroll 4
    for (int j = 0; j < 128; ++j) {
        float4 qv = *(const float4*)(sp + j * 4);
        float d = n1 + qv.w - 2.0f * (x1 * qv.x + y1 * qv.y + z1 * qv.z);
        int s = part * 128 + j;
        bool c2 = d < d2, c1 = d < d1, c0 = d < d0;
        d2 = c1 ? d1 : (c2 ? d : d2); i2 = c1 ? i1 : (c2 ? s : i2);
        d1 = c0 ? d0 : (c1 ? d : d1); i1 = c0 ? i0 : (c1 ? s : i1);
        d0 = c0 ? d  : d0;            i0 = c0 ? s  : i0;
    }
#pragma unroll
    for (int m = 1; m <= 4; m <<= 1) {
        float e0 = __shfl_xor(d0, m, 64), e1 = __shfl_xor(d1, m, 64), e2 = __shfl_xor(d2, m, 64);
        int   j0 = __shfl_xor(i0, m, 64), j1 = __shfl_xor(i1, m, 64), j2 = __shfl_xor(i2, m, 64);
        bool pref = (part < (part ^ m));
        merge3(d0, d1, d2, i0, i1, i2, e0, e1, e2, j0, j1, j2, pref);
    }
    if (part == 0) {
        float r0 = 1.0f / (d0 + 1e-8f), r1 = 1.0f / (d1 + 1e-8f), r2 = 1.0f / (d2 + 1e-8f);
        float rs = 1.0f / (r0 + r1 + r2);
        sIdx[q * 3 + 0] = i0; sIdx[q * 3 + 1] = i1; sIdx[q * 3 + 2] = i2;
        sW[q * 3 + 0] = r0 * rs; sW[q * 3 + 1] = r1 * rs; sW[q * 3 + 2] = r2 * rs;
    }
    __syncthreads();

    // build: 32 points x 64 lanes = 8 iterations of 256 threads
    int lane = tid & 63;
    int c = lane * 4;
#pragma unroll
    for (int it = 0; it < 8; ++it) {
        int lp = it * 4 + (tid >> 6);
        int pt = bn0 + lp;
        int j0 = sIdx[lp * 3], j1 = sIdx[lp * 3 + 1], j2 = sIdx[lp * 3 + 2];
        float w0 = sW[lp * 3], w1 = sW[lp * 3 + 1], w2 = sW[lp * 3 + 2];
        if (isf) {
            const float* p1 = (const float*)points1_ + (size_t)pt * D1;
            float2 v = *(const float2*)(p1 + lane * 2);
            ((unsigned int*)(X + (size_t)pt * KIN))[lane] =
                (unsigned int)f2bf(v.x) | ((unsigned int)f2bf(v.y) << 16);
            const float* base = (const float*)points2_;
            float4 a0 = *(const float4*)(base + ((size_t)(b * Ss + j0)) * D2 + c);
            float4 a1 = *(const float4*)(base + ((size_t)(b * Ss + j1)) * D2 + c);
            float4 a2 = *(const float4*)(base + ((size_t)(b * Ss + j2)) * D2 + c);
            uint2 out;
            unsigned short* uo = (unsigned short*)&out;
            uo[0] = f2bf(w0 * a0.x + w1 * a1.x + w2 * a2.x);
            uo[1] = f2bf(w0 * a0.y + w1 * a1.y + w2 * a2.y);
            uo[2] = f2bf(w0 * a0.z + w1 * a1.z + w2 * a2.z);
            uo[3] = f2bf(w0 * a0.w + w1 * a1.w + w2 * a2.w);
            *(uint2*)(X + (size_t)pt * KIN + D1 + c) = out;
        } else {
            const unsigned short* p1 = (const unsigned short*)points1_;
            ((unsigned int*)(X + (size_t)pt * KIN))[lane] =
                ((const unsigned int*)(p1 + (size_t)pt * D1))[lane];
            const unsigned short* base = (const unsigned short*)points2_;
            uint2 v0 = *(const uint2*)(base + ((size_t)(b * Ss + j0)) * D2 + c);
            uint2 v1 = *(const uint2*)(base + ((size_t)(b * Ss + j1)) * D2 + c);
            uint2 v2 = *(const uint2*)(base + ((size_t)(b * Ss + j2)) * D2 + c);
            const unsigned short* u0 = (const unsigned short*)&v0;
            const unsigned short* u1 = (const unsigned short*)&v1;
            const unsigned short* u2 = (const unsigned short*)&v2;
            uint2 out;
            unsigned short* uo = (unsigned short*)&out;
#pragma unroll
            for (int j = 0; j < 4; ++j)
                uo[j] = f2bf(w0 * bf2f(u0[j]) + w1 * bf2f(u1[j]) + w2 * bf2f(u2[j]));
            *(uint2*)(X + (size_t)pt * KIN + D1 + c) = out;
        }
    }
}

// ---------------- GEMM: C[l][o] = sum_c act(A[l][c]) * W[o][c], + channel stats ----------------
// 64-row x 256-col tile per block; ACT: prologue computes BN coeffs (cA,cC) from
// the PREVIOUS layer's stats inline (k_finalize launches eliminated), then staging
// applies gelu(cA*x+cC).
template <int K, int ACT>
__global__ __launch_bounds__(256) void k_gemm(const unsigned short* __restrict__ A,
                                              const unsigned short* __restrict__ W,
                                              unsigned short* __restrict__ Out,
                                              float* __restrict__ S1, float* __restrict__ S2,
                                              const float* __restrict__ S1in,
                                              const float* __restrict__ S2in,
                                              const void* __restrict__ g_,
                                              const void* __restrict__ bt_,
                                              const int* __restrict__ dflag) {
    __shared__ alignas(16) unsigned short As[64 * 64];    // 8 KB
    __shared__ alignas(16) unsigned short Bs[256 * 64];   // 32 KB
    __shared__ float sS1[256], sS2[256];
    __shared__ float sCA[256], sCC[256];

    int tid = threadIdx.x;
    int l0 = blockIdx.x * 64;
    int wn = tid >> 6, lane = tid & 63, quad = lane >> 4, lr = lane & 15;

    if (ACT) {
        int o = tid;
        float m = S1in[o] * (1.0f / (float)L);
        float var = S2in[o] * (1.0f / (float)L) - m * m;
        float g, bt;
        if (*dflag) { g = ((const float*)g_)[o]; bt = ((const float*)bt_)[o]; }
        else { g = bf2f(((const unsigned short*)g_)[o]); bt = bf2f(((const unsigned short*)bt_)[o]); }
        float a = g * rsqrtf(var + BN_EPS);
        sCA[o] = a;
        sCC[o] = bt - m * a;
    }

    floatx4 zero4 = {0.f, 0.f, 0.f, 0.f};
    floatx4 acc[4][4];
#pragma unroll
    for (int mi = 0; mi < 4; ++mi)
#pragma unroll
        for (int ni = 0; ni < 4; ++ni) acc[mi][ni] = zero4;

    constexpr int KC = K / 64;
    for (int kc = 0; kc < KC; ++kc) {
        __syncthreads();
#pragma unroll
        for (int it = 0; it < 2; ++it) {
            int idx = it * 256 + tid;
            int row = idx >> 3, c8 = idx & 7;
            union { uint4 v; unsigned short u[8]; } va;
            va.v = *(const uint4*)(A + (size_t)(l0 + row) * K + kc * 64 + c8 * 8);
            if (ACT) {
                int kbase = kc * 64 + c8 * 8;
#pragma unroll
                for (int j = 0; j < 8; ++j) {
                    float f = bf2f(va.u[j]);
                    va.u[j] = f2bf(gelu_f(sCA[kbase + j] * f + sCC[kbase + j]));
                }
            }
            *(uint4*)&As[row * 64 + ((c8 ^ (row & 7)) << 3)] = va.v;
        }
#pragma unroll
        for (int it = 0; it < 8; ++it) {
            int idx = it * 256 + tid;
            int row = idx >> 3, c8 = idx & 7;
            uint4 vb = *(const uint4*)(W + (size_t)row * K + kc * 64 + c8 * 8);
            *(uint4*)&Bs[row * 64 + ((c8 ^ (row & 7)) << 3)] = vb;
        }
        __syncthreads();
#pragma unroll
        for (int ks8 = 0; ks8 < 2; ++ks8) {
            bf16x8 af[4], bfr[4];
#pragma unroll
            for (int mi = 0; mi < 4; ++mi) {
                int ra = mi * 16 + lr;
                af[mi] = *(const bf16x8*)&As[ra * 64 + ((((ks8 << 2) + quad) ^ (ra & 7)) << 3)];
            }
#pragma unroll
            for (int ni = 0; ni < 4; ++ni) {
                int rb = wn * 64 + ni * 16 + lr;
                bfr[ni] = *(const bf16x8*)&Bs[rb * 64 + ((((ks8 << 2) + quad) ^ (rb & 7)) << 3)];
            }
#pragma unroll
            for (int mi = 0; mi < 4; ++mi)
#pragma unroll
                for (int ni = 0; ni < 4; ++ni)
                    acc[mi][ni] = __builtin_amdgcn_mfma_f32_16x16x32_bf16(af[mi], bfr[ni], acc[mi][ni], 0, 0, 0);
        }
    }

    float p1[4] = {0, 0, 0, 0}, p2[4] = {0, 0, 0, 0};
#pragma unroll
    for (int mi = 0; mi < 4; ++mi) {
#pragma unroll
        for (int ni = 0; ni < 4; ++ni) {
#pragma unroll
            for (int r = 0; r < 4; ++r) {
                float v = acc[mi][ni][r];
                int row = l0 + mi * 16 + quad * 4 + r;
                int col = wn * 64 + ni * 16 + lr;
                Out[(size_t)row * OC + col] = f2bf(v);
                p1[ni] += v;
                p2[ni] += v * v;
            }
        }
    }
    sS1[tid] = 0.f; sS2[tid] = 0.f;
    __syncthreads();
#pragma unroll
    for (int ni = 0; ni < 4; ++ni) {
        atomicAdd(&sS1[wn * 64 + ni * 16 + lr], p1[ni]);
        atomicAdd(&sS2[wn * 64 + ni * 16 + lr], p2[ni]);
    }
    __syncthreads();
    atomicAdd(&S1[tid], sS1[tid]);
    atomicAdd(&S2[tid], sS2[tid]);
}

// ---------------- final: out = gelu( bn2(t2) + gelu(bn0(t0)) ); BN coeffs inline ----------------
__global__ __launch_bounds__(256) void k_final(const unsigned short* __restrict__ t0,
                                               const unsigned short* __restrict__ t2,
                                               const float* __restrict__ S1_0, const float* __restrict__ S2_0,
                                               const float* __restrict__ S1_2, const float* __restrict__ S2_2,
                                               const void* __restrict__ g0_, const void* __restrict__ bt0_,
                                               const void* __restrict__ g2_, const void* __restrict__ bt2_,
                                               const int* __restrict__ dflag,
                                               void* __restrict__ out_) {
    __shared__ float sA0[256], sC0[256], sA2[256], sC2[256];
    int tid = threadIdx.x;
    bool isf = (*dflag != 0);
    {
        int o = tid;
        float m0 = S1_0[o] * (1.0f / (float)L);
        float v0_ = S2_0[o] * (1.0f / (float)L) - m0 * m0;
        float m2 = S1_2[o] * (1.0f / (float)L);
        float v2_ = S2_2[o] * (1.0f / (float)L) - m2 * m2;
        float g0, b0, g2, b2;
        if (isf) {
            g0 = ((const float*)g0_)[o]; b0 = ((const float*)bt0_)[o];
            g2 = ((const float*)g2_)[o]; b2 = ((const float*)bt2_)[o];
        } else {
            g0 = bf2f(((const unsigned short*)g0_)[o]); b0 = bf2f(((const unsigned short*)bt0_)[o]);
            g2 = bf2f(((const unsigned short*)g2_)[o]); b2 = bf2f(((const unsigned short*)bt2_)[o]);
        }
        float a0 = g0 * rsqrtf(v0_ + BN_EPS);
        float a2 = g2 * rsqrtf(v2_ + BN_EPS);
        sA0[o] = a0; sC0[o] = b0 - m0 * a0;
        sA2[o] = a2; sC2[o] = b2 - m2 * a2;
    }
    __syncthreads();

    int idx = (blockIdx.x * 256 + tid) * 8;
    int col = idx & (OC - 1);
    union { uint4 v; unsigned short u[8]; } v0, v2;
    v0.v = *(const uint4*)(t0 + idx);
    v2.v = *(const uint4*)(t2 + idx);
    float r[8];
#pragma unroll
    for (int j = 0; j < 8; ++j) {
        float x = gelu_f(sA0[col + j] * bf2f(v0.u[j]) + sC0[col + j]);
        float y = sA2[col + j] * bf2f(v2.u[j]) + sC2[col + j];
        r[j] = gelu_f(x + y);
    }
    if (isf) {
        float* o = (float*)out_ + idx;
        float4 lo = {r[0], r[1], r[2], r[3]};
        float4 hi = {r[4], r[5], r[6], r[7]};
        *(float4*)o = lo;
        *(float4*)(o + 4) = hi;
    } else {
        union { uint4 v; unsigned short u[8]; } vo;
#pragma unroll
        for (int j = 0; j < 8; ++j) vo.u[j] = f2bf(r[j]);
        *(uint4*)((unsigned short*)out_ + idx) = vo.v;
    }
}

extern "C" void kernel_launch(void* const* d_in, const int* in_sizes, int n_in,
                              void* d_out, int out_size, void* d_ws, size_t ws_size,
                              hipStream_t stream) {
    const void* xyz1    = d_in[0];
    const void* xyz2    = d_in[1];
    const void* points1 = d_in[2];
    const void* points2 = d_in[3];
    const void* W_fuse  = d_in[4];
    const void* g_fuse  = d_in[6];
    const void* bt_fuse = d_in[7];
    const void* W1      = d_in[8];
    const void* g1      = d_in[10];
    const void* bt1     = d_in[11];
    const void* W2      = d_in[12];
    const void* g2      = d_in[14];
    const void* bt2     = d_in[15];

    char* ws = (char*)d_ws;
    unsigned short* X  = (unsigned short*)ws;
    unsigned short* t0 = (unsigned short*)(ws + 25165824);
    unsigned short* t1 = (unsigned short*)d_out;   // d_out as bf16 scratch until k_final
    unsigned short* t2 = X;                        // X dead after GEMM1
    float* stats  = (float*)(ws + 42729472);
    int*   dflag  = (int*)(ws + 42729472 + 3072 * 4);
    unsigned short* Wf_bf = (unsigned short*)(ws + 42745856);  // contiguous: Wf | W1 | W2

    float *S1_0 = stats,        *S2_0 = stats + 256;
    float *S1_1 = stats + 512,  *S2_1 = stats + 768;
    float *S1_2 = stats + 1024, *S2_2 = stats + 1280;

    // launch 1: zero-stats + weight prep + fused nn/build  (6 + 896 + 1024 blocks)
    k_front<<<1926, 256, 0, stream>>>(xyz1, xyz2, points1, points2,
                                      W_fuse, W1, W2, Wf_bf, X, stats, dflag);
    // launches 2-4: GEMMs (BN-finalize folded into consumer prologues)
    k_gemm<KIN, 0><<<L / 64, 256, 0, stream>>>(X, Wf_bf, t0, S1_0, S2_0,
                                               nullptr, nullptr, nullptr, nullptr, nullptr);
    k_gemm<OC, 1><<<L / 64, 256, 0, stream>>>(t0, Wf_bf + 98304, t1, S1_1, S2_1,
                                              S1_0, S2_0, g_fuse, bt_fuse, dflag);
    k_gemm<OC, 1><<<L / 64, 256, 0, stream>>>(t1, Wf_bf + 163840, t2, S1_2, S2_2,
                                              S1_1, S2_1, g1, bt1, dflag);
    // launch 5: final elementwise (both BN coeff sets computed inline)
    k_final<<<L * OC / (256 * 8), 256, 0, stream>>>(t0, t2, S1_0, S2_0, S1_2, S2_2,
                                                    g_fuse, bt_fuse, g2, bt2, dflag, d_out);
}

// Round 9
// 233.011 us; speedup vs baseline: 1.0633x; 1.0014x over previous
//
#include <hip/hip_runtime.h>
#include <hip/hip_bf16.h>

// Problem constants
constexpr int Bb = 8, Nn = 4096, Ss = 1024;
constexpr int D1 = 128, D2 = 256, KIN = 384, OC = 256;
constexpr int L = Bb * Nn;             // 32768 rows
constexpr float BN_EPS = 1e-5f;

typedef __attribute__((ext_vector_type(4))) float floatx4;
typedef __attribute__((ext_vector_type(8))) __bf16 bf16x8;

#define DEV __device__ __forceinline__

DEV float bf2f(unsigned short u) {
    union { unsigned int i; float f; } v; v.i = ((unsigned int)u) << 16; return v.f;
}
DEV unsigned short f2bf(float f) {
    union { float f; unsigned int i; } v; v.f = f;
    unsigned int x = v.i;
    return (unsigned short)((x + 0x7FFFu + ((x >> 16) & 1u)) >> 16);  // RNE
}
// Fast tanh-form gelu: x*sigmoid(2u), u = sqrt(2/pi)*(x+0.044715x^3).
DEV float gelu_f(float x) {
    float u = x * (0.7978845608f + 0.0356774081f * x * x);
    float t = __expf(-2.0f * u);
    return x * __builtin_amdgcn_rcpf(1.0f + t);
}

// Per-block dtype probe (f32 low-halves are mantissa junk; bf16 pairs are sane).
DEV bool probe_isf(const unsigned int* __restrict__ w, int tid) {
    unsigned int lo = w[tid & 63] & 0xFFFFu;
    int e = (int)((lo >> 7) & 0xFF);
    unsigned long long m = __ballot(e >= 100 && e <= 144);
    return __popcll(m) < 48;
}

// Branchless merge of two sorted (asc) top-3 lists; pref=true -> ties keep "a".
DEV void merge3(float& d0, float& d1, float& d2, int& i0, int& i1, int& i2,
                float e0, float e1, float e2, int j0, int j1, int j2, bool pref) {
    float a0 = d0, a1 = d1, a2 = d2; int x0 = i0, x1 = i1, x2 = i2;
    float b0 = e0, b1 = e1;          int y0 = j0, y1 = j1;
    bool t = pref ? (a0 <= b0) : (a0 < b0);
    d0 = t ? a0 : b0; i0 = t ? x0 : y0;
    a0 = t ? a1 : a0; x0 = t ? x1 : x0;
    a1 = t ? a2 : a1; x1 = t ? x2 : x1;
    b0 = t ? b0 : b1; y0 = t ? y0 : y1;
    b1 = t ? b1 : e2; y1 = t ? y1 : j2;
    t = pref ? (a0 <= b0) : (a0 < b0);
    d1 = t ? a0 : b0; i1 = t ? x0 : y0;
    a0 = t ? a1 : a0; x0 = t ? x1 : x0;
    b0 = t ? b0 : b1; y0 = t ? y0 : y1;
    t = pref ? (a0 <= b0) : (a0 < b0);
    d2 = t ? a0 : b0; i2 = t ? x0 : y0;
}

// ---------------- launch 1: zero-stats | prep-weights | 3-NN ----------------
// blocks [0,6): zero stats. blocks [6,902): weights->bf16. blocks [902,1926):
// 32 queries each, 8 lanes/query + shfl_xor merge; results to nn_idx/nn_w.
__global__ __launch_bounds__(256) void k_front(const void* __restrict__ xyz1_,
                                               const void* __restrict__ xyz2_,
                                               const void* __restrict__ w0_,
                                               const void* __restrict__ w1_,
                                               const void* __restrict__ w2_,
                                               unsigned short* __restrict__ Wdst,
                                               float* __restrict__ stats,
                                               int* __restrict__ dflag,
                                               int* __restrict__ nn_idx,
                                               float* __restrict__ nn_w) {
    int tid = threadIdx.x;
    int bid = blockIdx.x;
    bool isf = probe_isf((const unsigned int*)xyz1_, tid);

    if (bid < 6) {
        stats[bid * 256 + tid] = 0.0f;
        if (bid == 0 && tid == 0) *dflag = isf ? 1 : 0;
        return;
    }
    if (bid < 902) {
        int i = (bid - 6) * 256 + tid;
        const void* src; int off;
        if (i < 98304)       { src = w0_; off = i; }
        else if (i < 163840) { src = w1_; off = i - 98304; }
        else                 { src = w2_; off = i - 163840; }
        Wdst[i] = isf ? f2bf(((const float*)src)[off]) : ((const unsigned short*)src)[off];
        return;
    }

    __shared__ alignas(16) float s4[Ss * 4 + 32];
    int bn0 = (bid - 902) * 32;
    int b = bn0 >> 12;

    if (isf) {
        const float* p2 = (const float*)xyz2_ + (size_t)b * Ss * 3;
        for (int i = tid; i < Ss * 3; i += 256) {
            int s = i / 3, k = i - s * 3;
            s4[s * 4 + k + ((s >> 7) << 2)] = p2[i];
        }
    } else {
        const unsigned short* p2 = (const unsigned short*)xyz2_ + (size_t)b * Ss * 3;
        for (int i = tid; i < Ss * 3; i += 256) {
            int s = i / 3, k = i - s * 3;
            s4[s * 4 + k + ((s >> 7) << 2)] = bf2f(p2[i]);
        }
    }
    __syncthreads();
    for (int s = tid; s < Ss; s += 256) {
        int a = s * 4 + ((s >> 7) << 2);
        float x = s4[a], y = s4[a + 1], z = s4[a + 2];
        s4[a + 3] = x * x + y * y + z * z;
    }
    __syncthreads();

    int part = tid & 7;
    int bn = bn0 + (tid >> 3);
    float x1, y1, z1;
    if (isf) {
        const float* p1 = (const float*)xyz1_ + (size_t)bn * 3;
        x1 = p1[0]; y1 = p1[1]; z1 = p1[2];
    } else {
        const unsigned short* p1 = (const unsigned short*)xyz1_ + (size_t)bn * 3;
        x1 = bf2f(p1[0]); y1 = bf2f(p1[1]); z1 = bf2f(p1[2]);
    }
    float n1 = x1 * x1 + y1 * y1 + z1 * z1;

    float d0 = 3.4e38f, d1 = 3.4e38f, d2 = 3.4e38f;
    int i0 = 0, i1 = 0, i2 = 0;
    const float* sp = &s4[part * 516];
#pragma unroll 4
    for (int j = 0; j < 128; ++j) {
        float4 qv = *(const float4*)(sp + j * 4);
        float d = n1 + qv.w - 2.0f * (x1 * qv.x + y1 * qv.y + z1 * qv.z);
        int s = part * 128 + j;
        bool c2 = d < d2, c1 = d < d1, c0 = d < d0;
        d2 = c1 ? d1 : (c2 ? d : d2); i2 = c1 ? i1 : (c2 ? s : i2);
        d1 = c0 ? d0 : (c1 ? d : d1); i1 = c0 ? i0 : (c1 ? s : i1);
        d0 = c0 ? d  : d0;            i0 = c0 ? s  : i0;
    }
#pragma unroll
    for (int m = 1; m <= 4; m <<= 1) {
        float e0 = __shfl_xor(d0, m, 64), e1 = __shfl_xor(d1, m, 64), e2 = __shfl_xor(d2, m, 64);
        int   j0 = __shfl_xor(i0, m, 64), j1 = __shfl_xor(i1, m, 64), j2 = __shfl_xor(i2, m, 64);
        bool pref = (part < (part ^ m));
        merge3(d0, d1, d2, i0, i1, i2, e0, e1, e2, j0, j1, j2, pref);
    }
    if (part == 0) {
        float r0 = 1.0f / (d0 + 1e-8f), r1 = 1.0f / (d1 + 1e-8f), r2 = 1.0f / (d2 + 1e-8f);
        float rs = 1.0f / (r0 + r1 + r2);
        nn_idx[bn * 3 + 0] = i0; nn_idx[bn * 3 + 1] = i1; nn_idx[bn * 3 + 2] = i2;
        nn_w[bn * 3 + 0] = r0 * rs; nn_w[bn * 3 + 1] = r1 * rs; nn_w[bn * 3 + 2] = r2 * rs;
    }
}

// ---------------- launch 2: GEMM1 with A built on the fly ----------------
// A[l][c] = c<128 ? points1[l][c] : interp(points2)[l][c-128]; X never materialized.
// points2 is ~8.4 MB -> L2/L3 resident; gathers hit cache after first touch.
__global__ __launch_bounds__(256) void k_gemm1(const void* __restrict__ p1_,
                                               const void* __restrict__ p2_,
                                               const int* __restrict__ nn_idx,
                                               const float* __restrict__ nn_w,
                                               const int* __restrict__ dflag,
                                               const unsigned short* __restrict__ W,
                                               unsigned short* __restrict__ Out,
                                               float* __restrict__ S1, float* __restrict__ S2) {
    __shared__ alignas(16) unsigned short As[64 * 64];
    __shared__ alignas(16) unsigned short Bs[256 * 64];
    __shared__ float sS1[256], sS2[256];

    int tid = threadIdx.x;
    int l0 = blockIdx.x * 64;
    int wn = tid >> 6, lane = tid & 63, quad = lane >> 4, lr = lane & 15;
    bool isf = (*dflag != 0);

    floatx4 acc[4][4];
#pragma unroll
    for (int mi = 0; mi < 4; ++mi)
#pragma unroll
        for (int ni = 0; ni < 4; ++ni) acc[mi][ni] = (floatx4){0.f, 0.f, 0.f, 0.f};

    for (int kc = 0; kc < KIN / 64; ++kc) {
        __syncthreads();
#pragma unroll
        for (int it = 0; it < 2; ++it) {
            int idx = it * 256 + tid, row = idx >> 3, c8 = idx & 7;
            int pt = l0 + row;
            int c0 = kc * 64 + c8 * 8;
            union { uint4 v; unsigned short u[8]; } va;
            if (c0 < D1) {
                if (isf) {
                    const float* p = (const float*)p1_ + (size_t)pt * D1 + c0;
                    float4 f0 = *(const float4*)p;
                    float4 f1 = *(const float4*)(p + 4);
                    va.u[0] = f2bf(f0.x); va.u[1] = f2bf(f0.y); va.u[2] = f2bf(f0.z); va.u[3] = f2bf(f0.w);
                    va.u[4] = f2bf(f1.x); va.u[5] = f2bf(f1.y); va.u[6] = f2bf(f1.z); va.u[7] = f2bf(f1.w);
                } else {
                    va.v = *(const uint4*)((const unsigned short*)p1_ + (size_t)pt * D1 + c0);
                }
            } else {
                int c2 = c0 - D1;
                int b = pt >> 12;
                int j0 = nn_idx[pt * 3], j1 = nn_idx[pt * 3 + 1], j2 = nn_idx[pt * 3 + 2];
                float w0 = nn_w[pt * 3], w1 = nn_w[pt * 3 + 1], w2 = nn_w[pt * 3 + 2];
                if (isf) {
                    const float* base = (const float*)p2_;
                    const float* r0 = base + ((size_t)(b * Ss + j0)) * D2 + c2;
                    const float* r1 = base + ((size_t)(b * Ss + j1)) * D2 + c2;
                    const float* r2 = base + ((size_t)(b * Ss + j2)) * D2 + c2;
#pragma unroll
                    for (int h = 0; h < 2; ++h) {
                        float4 a0 = *(const float4*)(r0 + h * 4);
                        float4 a1 = *(const float4*)(r1 + h * 4);
                        float4 a2 = *(const float4*)(r2 + h * 4);
                        va.u[h * 4 + 0] = f2bf(w0 * a0.x + w1 * a1.x + w2 * a2.x);
                        va.u[h * 4 + 1] = f2bf(w0 * a0.y + w1 * a1.y + w2 * a2.y);
                        va.u[h * 4 + 2] = f2bf(w0 * a0.z + w1 * a1.z + w2 * a2.z);
                        va.u[h * 4 + 3] = f2bf(w0 * a0.w + w1 * a1.w + w2 * a2.w);
                    }
                } else {
                    const unsigned short* base = (const unsigned short*)p2_;
                    uint4 v0 = *(const uint4*)(base + ((size_t)(b * Ss + j0)) * D2 + c2);
                    uint4 v1 = *(const uint4*)(base + ((size_t)(b * Ss + j1)) * D2 + c2);
                    uint4 v2 = *(const uint4*)(base + ((size_t)(b * Ss + j2)) * D2 + c2);
                    const unsigned short* u0 = (const unsigned short*)&v0;
                    const unsigned short* u1 = (const unsigned short*)&v1;
                    const unsigned short* u2 = (const unsigned short*)&v2;
#pragma unroll
                    for (int j = 0; j < 8; ++j)
                        va.u[j] = f2bf(w0 * bf2f(u0[j]) + w1 * bf2f(u1[j]) + w2 * bf2f(u2[j]));
                }
            }
            *(uint4*)&As[row * 64 + ((c8 ^ (row & 7)) << 3)] = va.v;
        }
#pragma unroll
        for (int it = 0; it < 8; ++it) {
            int idx = it * 256 + tid, row = idx >> 3, c8 = idx & 7;
            uint4 vb = *(const uint4*)(W + (size_t)row * KIN + kc * 64 + c8 * 8);
            *(uint4*)&Bs[row * 64 + ((c8 ^ (row & 7)) << 3)] = vb;
        }
        __syncthreads();
#pragma unroll
        for (int ks8 = 0; ks8 < 2; ++ks8) {
            bf16x8 af[4], bfr[4];
#pragma unroll
            for (int mi = 0; mi < 4; ++mi) {
                int ra = mi * 16 + lr;
                af[mi] = *(const bf16x8*)&As[ra * 64 + ((((ks8 << 2) + quad) ^ (ra & 7)) << 3)];
            }
#pragma unroll
            for (int ni = 0; ni < 4; ++ni) {
                int rb = wn * 64 + ni * 16 + lr;
                bfr[ni] = *(const bf16x8*)&Bs[rb * 64 + ((((ks8 << 2) + quad) ^ (rb & 7)) << 3)];
            }
#pragma unroll
            for (int mi = 0; mi < 4; ++mi)
#pragma unroll
                for (int ni = 0; ni < 4; ++ni)
                    acc[mi][ni] = __builtin_amdgcn_mfma_f32_16x16x32_bf16(af[mi], bfr[ni], acc[mi][ni], 0, 0, 0);
        }
    }

    float p1a[4] = {0, 0, 0, 0}, p2a[4] = {0, 0, 0, 0};
#pragma unroll
    for (int mi = 0; mi < 4; ++mi)
#pragma unroll
        for (int ni = 0; ni < 4; ++ni)
#pragma unroll
            for (int r = 0; r < 4; ++r) {
                float v = acc[mi][ni][r];
                int row = l0 + mi * 16 + quad * 4 + r;
                int col = wn * 64 + ni * 16 + lr;
                Out[(size_t)row * OC + col] = f2bf(v);
                p1a[ni] += v; p2a[ni] += v * v;
            }
    sS1[tid] = 0.f; sS2[tid] = 0.f;
    __syncthreads();
#pragma unroll
    for (int ni = 0; ni < 4; ++ni) {
        atomicAdd(&sS1[wn * 64 + ni * 16 + lr], p1a[ni]);
        atomicAdd(&sS2[wn * 64 + ni * 16 + lr], p2a[ni]);
    }
    __syncthreads();
    atomicAdd(&S1[tid], sS1[tid]);
    atomicAdd(&S2[tid], sS2[tid]);
}

// ---------------- GEMM2/3: C = act(A)*W^T + stats; BN coeffs computed inline ----------------
template <int K>
__global__ __launch_bounds__(256) void k_gemm(const unsigned short* __restrict__ A,
                                              const unsigned short* __restrict__ W,
                                              unsigned short* __restrict__ Out,
                                              float* __restrict__ S1, float* __restrict__ S2,
                                              const float* __restrict__ S1in,
                                              const float* __restrict__ S2in,
                                              const void* __restrict__ g_,
                                              const void* __restrict__ bt_,
                                              const int* __restrict__ dflag) {
    __shared__ alignas(16) unsigned short As[64 * 64];
    __shared__ alignas(16) unsigned short Bs[256 * 64];
    __shared__ float sS1[256], sS2[256];
    __shared__ float sCA[256], sCC[256];

    int tid = threadIdx.x;
    int l0 = blockIdx.x * 64;
    int wn = tid >> 6, lane = tid & 63, quad = lane >> 4, lr = lane & 15;

    {
        float m = S1in[tid] * (1.0f / (float)L);
        float var = S2in[tid] * (1.0f / (float)L) - m * m;
        float g, bt;
        if (*dflag) { g = ((const float*)g_)[tid]; bt = ((const float*)bt_)[tid]; }
        else { g = bf2f(((const unsigned short*)g_)[tid]); bt = bf2f(((const unsigned short*)bt_)[tid]); }
        float a = g * rsqrtf(var + BN_EPS);
        sCA[tid] = a;
        sCC[tid] = bt - m * a;
    }

    floatx4 acc[4][4];
#pragma unroll
    for (int mi = 0; mi < 4; ++mi)
#pragma unroll
        for (int ni = 0; ni < 4; ++ni) acc[mi][ni] = (floatx4){0.f, 0.f, 0.f, 0.f};

    constexpr int KC = K / 64;
    for (int kc = 0; kc < KC; ++kc) {
        __syncthreads();
#pragma unroll
        for (int it = 0; it < 2; ++it) {
            int idx = it * 256 + tid, row = idx >> 3, c8 = idx & 7;
            union { uint4 v; unsigned short u[8]; } va;
            va.v = *(const uint4*)(A + (size_t)(l0 + row) * K + kc * 64 + c8 * 8);
            int kb = kc * 64 + c8 * 8;
#pragma unroll
            for (int j = 0; j < 8; ++j) {
                float f = bf2f(va.u[j]);
                va.u[j] = f2bf(gelu_f(sCA[kb + j] * f + sCC[kb + j]));
            }
            *(uint4*)&As[row * 64 + ((c8 ^ (row & 7)) << 3)] = va.v;
        }
#pragma unroll
        for (int it = 0; it < 8; ++it) {
            int idx = it * 256 + tid, row = idx >> 3, c8 = idx & 7;
            uint4 vb = *(const uint4*)(W + (size_t)row * K + kc * 64 + c8 * 8);
            *(uint4*)&Bs[row * 64 + ((c8 ^ (row & 7)) << 3)] = vb;
        }
        __syncthreads();
#pragma unroll
        for (int ks8 = 0; ks8 < 2; ++ks8) {
            bf16x8 af[4], bfr[4];
#pragma unroll
            for (int mi = 0; mi < 4; ++mi) {
                int ra = mi * 16 + lr;
                af[mi] = *(const bf16x8*)&As[ra * 64 + ((((ks8 << 2) + quad) ^ (ra & 7)) << 3)];
            }
#pragma unroll
            for (int ni = 0; ni < 4; ++ni) {
                int rb = wn * 64 + ni * 16 + lr;
                bfr[ni] = *(const bf16x8*)&Bs[rb * 64 + ((((ks8 << 2) + quad) ^ (rb & 7)) << 3)];
            }
#pragma unroll
            for (int mi = 0; mi < 4; ++mi)
#pragma unroll
                for (int ni = 0; ni < 4; ++ni)
                    acc[mi][ni] = __builtin_amdgcn_mfma_f32_16x16x32_bf16(af[mi], bfr[ni], acc[mi][ni], 0, 0, 0);
        }
    }

    float p1a[4] = {0, 0, 0, 0}, p2a[4] = {0, 0, 0, 0};
#pragma unroll
    for (int mi = 0; mi < 4; ++mi)
#pragma unroll
        for (int ni = 0; ni < 4; ++ni)
#pragma unroll
            for (int r = 0; r < 4; ++r) {
                float v = acc[mi][ni][r];
                int row = l0 + mi * 16 + quad * 4 + r;
                int col = wn * 64 + ni * 16 + lr;
                Out[(size_t)row * OC + col] = f2bf(v);
                p1a[ni] += v; p2a[ni] += v * v;
            }
    sS1[tid] = 0.f; sS2[tid] = 0.f;
    __syncthreads();
#pragma unroll
    for (int ni = 0; ni < 4; ++ni) {
        atomicAdd(&sS1[wn * 64 + ni * 16 + lr], p1a[ni]);
        atomicAdd(&sS2[wn * 64 + ni * 16 + lr], p2a[ni]);
    }
    __syncthreads();
    atomicAdd(&S1[tid], sS1[tid]);
    atomicAdd(&S2[tid], sS2[tid]);
}

// ---------------- launch 5: out = gelu( bn2(t2) + gelu(bn0(t0)) ); BN coeffs inline ----------------
__global__ __launch_bounds__(256) void k_final(const unsigned short* __restrict__ t0,
                                               const unsigned short* __restrict__ t2,
                                               const float* __restrict__ S1_0, const float* __restrict__ S2_0,
                                               const float* __restrict__ S1_2, const float* __restrict__ S2_2,
                                               const void* __restrict__ g0_, const void* __restrict__ bt0_,
                                               const void* __restrict__ g2_, const void* __restrict__ bt2_,
                                               const int* __restrict__ dflag,
                                               void* __restrict__ out_) {
    __shared__ float sA0[256], sC0[256], sA2[256], sC2[256];
    int tid = threadIdx.x;
    bool isf = (*dflag != 0);
    {
        float m0 = S1_0[tid] * (1.0f / (float)L);
        float v0_ = S2_0[tid] * (1.0f / (float)L) - m0 * m0;
        float m2 = S1_2[tid] * (1.0f / (float)L);
        float v2_ = S2_2[tid] * (1.0f / (float)L) - m2 * m2;
        float g0, b0, g2, b2;
        if (isf) {
            g0 = ((const float*)g0_)[tid]; b0 = ((const float*)bt0_)[tid];
            g2 = ((const float*)g2_)[tid]; b2 = ((const float*)bt2_)[tid];
        } else {
            g0 = bf2f(((const unsigned short*)g0_)[tid]); b0 = bf2f(((const unsigned short*)bt0_)[tid]);
            g2 = bf2f(((const unsigned short*)g2_)[tid]); b2 = bf2f(((const unsigned short*)bt2_)[tid]);
        }
        float a0 = g0 * rsqrtf(v0_ + BN_EPS);
        float a2 = g2 * rsqrtf(v2_ + BN_EPS);
        sA0[tid] = a0; sC0[tid] = b0 - m0 * a0;
        sA2[tid] = a2; sC2[tid] = b2 - m2 * a2;
    }
    __syncthreads();

    int idx = (blockIdx.x * 256 + tid) * 8;
    int col = idx & (OC - 1);
    union { uint4 v; unsigned short u[8]; } v0, v2;
    v0.v = *(const uint4*)(t0 + idx);
    v2.v = *(const uint4*)(t2 + idx);
    float r[8];
#pragma unroll
    for (int j = 0; j < 8; ++j) {
        float x = gelu_f(sA0[col + j] * bf2f(v0.u[j]) + sC0[col + j]);
        float y = sA2[col + j] * bf2f(v2.u[j]) + sC2[col + j];
        r[j] = gelu_f(x + y);
    }
    if (isf) {
        float* o = (float*)out_ + idx;
        float4 lo = {r[0], r[1], r[2], r[3]};
        float4 hi = {r[4], r[5], r[6], r[7]};
        *(float4*)o = lo;
        *(float4*)(o + 4) = hi;
    } else {
        union { uint4 v; unsigned short u[8]; } vo;
#pragma unroll
        for (int j = 0; j < 8; ++j) vo.u[j] = f2bf(r[j]);
        *(uint4*)((unsigned short*)out_ + idx) = vo.v;
    }
}

extern "C" void kernel_launch(void* const* d_in, const int* in_sizes, int n_in,
                              void* d_out, int out_size, void* d_ws, size_t ws_size,
                              hipStream_t stream) {
    const void* xyz1    = d_in[0];
    const void* xyz2    = d_in[1];
    const void* points1 = d_in[2];
    const void* points2 = d_in[3];
    const void* W_fuse  = d_in[4];
    const void* g_fuse  = d_in[6];
    const void* bt_fuse = d_in[7];
    const void* W1      = d_in[8];
    const void* g1      = d_in[10];
    const void* bt1     = d_in[11];
    const void* W2      = d_in[12];
    const void* g2      = d_in[14];
    const void* bt2     = d_in[15];

    char* ws = (char*)d_ws;
    unsigned short* t2 = (unsigned short*)ws;               // 16.8 MB (old X region)
    unsigned short* t0 = (unsigned short*)(ws + 25165824);
    unsigned short* t1 = (unsigned short*)d_out;            // d_out as bf16 scratch until k_final
    int*   nn_idx = (int*)(ws + 41943040);
    float* nn_w   = (float*)(ws + 42336256);
    float* stats  = (float*)(ws + 42729472);
    int*   dflag  = (int*)(ws + 42729472 + 3072 * 4);
    unsigned short* Wbf = (unsigned short*)(ws + 42745856); // Wf | W1 | W2 contiguous

    float *S1_0 = stats,        *S2_0 = stats + 256;
    float *S1_1 = stats + 512,  *S2_1 = stats + 768;
    float *S1_2 = stats + 1024, *S2_2 = stats + 1280;

    // launch 1: zero-stats + weight prep + 3-NN
    k_front<<<1926, 256, 0, stream>>>(xyz1, xyz2, W_fuse, W1, W2, Wbf, stats, dflag, nn_idx, nn_w);
    // launch 2: GEMM1 with fused interp/concat (X never materialized)
    k_gemm1<<<L / 64, 256, 0, stream>>>(points1, points2, nn_idx, nn_w, dflag,
                                        Wbf, t0, S1_0, S2_0);
    // launches 3-4: GEMM2/3 with BN+gelu staging
    k_gemm<OC><<<L / 64, 256, 0, stream>>>(t0, Wbf + 98304, t1, S1_1, S2_1,
                                           S1_0, S2_0, g_fuse, bt_fuse, dflag);
    k_gemm<OC><<<L / 64, 256, 0, stream>>>(t1, Wbf + 163840, t2, S1_2, S2_2,
                                           S1_1, S2_1, g1, bt1, dflag);
    // launch 5: final elementwise
    k_final<<<L * OC / (256 * 8), 256, 0, stream>>>(t0, t2, S1_0, S2_0, S1_2, S2_2,
                                                    g_fuse, bt_fuse, g2, bt2, dflag, d_out);
}